// Round 4
// baseline (1709.709 us; speedup 1.0000x reference)
//
#include <hip/hip_runtime.h>

// GCN 2-layer via CSR gather (no float atomics).
// R4: replaced broadcast-load GEMM with LDS-tiled register-blocked GEMM.

// ---------------- degree ----------------
__global__ void deg_kernel(const int* __restrict__ dst, int E, int* __restrict__ deg) {
    int e = blockIdx.x * blockDim.x + threadIdx.x;
    if (e < E) atomicAdd(&deg[dst[e]], 1);
}

__global__ void dinv_kernel(const int* __restrict__ deg, float* __restrict__ dinv, int N) {
    int i = blockIdx.x * blockDim.x + threadIdx.x;
    if (i < N) dinv[i] = rsqrtf((float)deg[i] + 1.0f);  // +1 = self-loop
}

// ---------------- scan: offs = exclusive_scan(deg), offs[N] = E ----------------
__global__ void blocksum_kernel(const int* __restrict__ deg, int N, int* __restrict__ bsum) {
    __shared__ int s[256];
    int i = blockIdx.x * 256 + threadIdx.x;
    s[threadIdx.x] = (i < N) ? deg[i] : 0;
    __syncthreads();
    for (int o = 128; o > 0; o >>= 1) {
        if (threadIdx.x < o) s[threadIdx.x] += s[threadIdx.x + o];
        __syncthreads();
    }
    if (threadIdx.x == 0) bsum[blockIdx.x] = s[0];
}

__global__ void scan_bsum_kernel(int* __restrict__ bsum, int NB) {
    __shared__ int s[1024];
    int t = threadIdx.x;
    int v = (t < NB) ? bsum[t] : 0;
    s[t] = v;
    __syncthreads();
    for (int off = 1; off < 1024; off <<= 1) {
        int x = (t >= off) ? s[t - off] : 0;
        __syncthreads();
        s[t] += x;
        __syncthreads();
    }
    if (t < NB) bsum[t] = s[t] - v;  // exclusive, in place
}

__global__ void offsets_kernel(const int* __restrict__ deg, const int* __restrict__ bsum,
                               int* __restrict__ offs, int N, int E) {
    __shared__ int s[256];
    int t = threadIdx.x;
    int i = blockIdx.x * 256 + t;
    int v = (i < N) ? deg[i] : 0;
    s[t] = v;
    __syncthreads();
    for (int off = 1; off < 256; off <<= 1) {
        int x = (t >= off) ? s[t - off] : 0;
        __syncthreads();
        s[t] += x;
        __syncthreads();
    }
    if (i < N) offs[i] = bsum[blockIdx.x] + s[t] - v;
    if (i == 0) offs[N] = E;
}

__global__ void copy_kernel(const int* __restrict__ a, int* __restrict__ b, int N) {
    int i = blockIdx.x * blockDim.x + threadIdx.x;
    if (i < N) b[i] = a[i];
}

// ---------------- CSR fill: csr_src grouped by dst ----------------
__global__ void fill_kernel(const int* __restrict__ src, const int* __restrict__ dst, int E,
                            int* __restrict__ cursor, int* __restrict__ csr_src) {
    int e = blockIdx.x * blockDim.x + threadIdx.x;
    if (e < E) {
        int pos = atomicAdd(&cursor[dst[e]], 1);
        csr_src[pos] = src[e];
    }
}

// ---------------- LDS-tiled GEMM: out[r,c] = (A[r,:]@W[:,c]) * dinv[r] ----------------
// 256 threads, BR=64 rows/block, each thread computes RB x CB outputs.
template <int K, int C, int RB, int CB>
__global__ void gemm_tile_kernel(const float* __restrict__ A, const float* __restrict__ W,
                                 const float* __restrict__ dinv, float* __restrict__ out, int N) {
    constexpr int BR = 64;
    constexpr int AL = K + 4;            // padded A row (floats); +4 keeps float4 align, breaks pow2 stride
    constexpr int F4R = K / 4;           // float4 per A row
    constexpr int CG = C / CB;           // column groups
    __shared__ float Wl[K * C];
    __shared__ float Al[BR * AL];

    const int t = threadIdx.x;
    // stage W [K][C] row-major
    for (int i = t; i < K * C / 4; i += 256) ((float4*)Wl)[i] = ((const float4*)W)[i];
    // stage A tile (coalesced: consecutive threads -> consecutive float4 within row)
    const int row0 = blockIdx.x * BR;
    for (int i = t; i < BR * F4R; i += 256) {
        int r = i / F4R, k4 = i % F4R;
        float4 v = make_float4(0.f, 0.f, 0.f, 0.f);
        if (row0 + r < N) v = ((const float4*)(A + (size_t)(row0 + r) * K))[k4];
        *(float4*)(Al + r * AL + k4 * 4) = v;
    }
    __syncthreads();

    const int c0 = (t % CG) * CB;        // CB==4 assumed for float4 W reads
    const int r0 = (t / CG) * RB;
    float acc[RB][CB];
#pragma unroll
    for (int i = 0; i < RB; ++i)
#pragma unroll
        for (int j = 0; j < CB; ++j) acc[i][j] = 0.f;

#pragma unroll
    for (int k4 = 0; k4 < K / 4; ++k4) {
        float4 a[RB];
#pragma unroll
        for (int i = 0; i < RB; ++i) a[i] = *(const float4*)(Al + (r0 + i) * AL + k4 * 4);
#pragma unroll
        for (int j = 0; j < 4; ++j) {
            float4 w = *(const float4*)(Wl + (k4 * 4 + j) * C + c0);
#pragma unroll
            for (int i = 0; i < RB; ++i) {
                float av = ((const float*)&a[i])[j];
                acc[i][0] += av * w.x;
                acc[i][1] += av * w.y;
                acc[i][2] += av * w.z;
                acc[i][3] += av * w.w;
            }
        }
    }

#pragma unroll
    for (int i = 0; i < RB; ++i) {
        int row = row0 + r0 + i;
        if (row < N) {
            float d = dinv[row];
            float4 r;
            r.x = acc[i][0] * d;
            r.y = acc[i][1] * d;
            r.z = acc[i][2] * d;
            r.w = acc[i][3] * d;
            *(float4*)(out + (size_t)row * C + c0) = r;
        }
    }
}

// ---------------- gather: out[d] = dinv[d]*(sum_{s in N(d)} hs[s] + hs[d]) + b, optional relu
template <int C, bool RELU>
__global__ void gather_kernel(const float* __restrict__ hs, const float* __restrict__ dinv,
                              const int* __restrict__ offs, const int* __restrict__ csr_src,
                              const float* __restrict__ b, float* __restrict__ out, int N) {
    int gtid = blockIdx.x * blockDim.x + threadIdx.x;
    int lane = gtid % C;
    int d = gtid / C;
    if (d >= N) return;
    float acc = hs[(size_t)d * C + lane];  // self-loop term
    int beg = offs[d];
    int end = offs[d + 1];
    int j = beg;
    for (; j + 1 < end; j += 2) {
        int s0 = csr_src[j];
        int s1 = csr_src[j + 1];
        float v0 = hs[(size_t)s0 * C + lane];
        float v1 = hs[(size_t)s1 * C + lane];
        acc += v0;
        acc += v1;
    }
    if (j < end) acc += hs[(size_t)csr_src[j] * C + lane];
    float r = acc * dinv[d] + b[lane];
    if (RELU) r = fmaxf(r, 0.f);
    out[(size_t)d * C + lane] = r;
}

extern "C" void kernel_launch(void* const* d_in, const int* in_sizes, int n_in,
                              void* d_out, int out_size, void* d_ws, size_t ws_size,
                              hipStream_t stream) {
    const float* x = (const float*)d_in[0];
    const int* ei = (const int*)d_in[1];
    const float* W1 = (const float*)d_in[2];
    const float* b1 = (const float*)d_in[3];
    const float* W2 = (const float*)d_in[4];
    const float* b2 = (const float*)d_in[5];

    const int N = in_sizes[0] / 128;  // 100000
    const int E = in_sizes[1] / 2;    // 1600000
    const int* src = ei;
    const int* dst = ei + E;
    const int NB = (N + 255) / 256;   // 391 scan blocks (<= 1024)

    // workspace layout (4-byte elements)
    int* deg = (int*)d_ws;                         // N
    float* dinv = (float*)(deg + NB * 256);        // N
    int* offs = (int*)(dinv + NB * 256);           // N+1 (pad to 256)
    int* cursor = offs + NB * 256 + 256;           // N
    int* bsum = cursor + NB * 256;                 // NB (pad 1024)
    int* csr_src = bsum + 1024;                    // E
    float* h1s = (float*)(csr_src + ((E + 63) & ~63));  // N*64
    float* h2 = h1s + (size_t)N * 64;              // N*64
    float* h3s = h1s;                              // reuse h1s (N*32)
    float* out = (float*)d_out;

    // 1) degrees -> dinv
    hipMemsetAsync(deg, 0, (size_t)N * 4, stream);
    deg_kernel<<<(E + 255) / 256, 256, 0, stream>>>(dst, E, deg);
    dinv_kernel<<<NB, 256, 0, stream>>>(deg, dinv, N);

    // 2) CSR: offs = exscan(deg); fill csr_src grouped by dst
    blocksum_kernel<<<NB, 256, 0, stream>>>(deg, N, bsum);
    scan_bsum_kernel<<<1, 1024, 0, stream>>>(bsum, NB);
    offsets_kernel<<<NB, 256, 0, stream>>>(deg, bsum, offs, N, E);
    copy_kernel<<<NB, 256, 0, stream>>>(offs, cursor, N);
    fill_kernel<<<(E + 255) / 256, 256, 0, stream>>>(src, dst, E, cursor, csr_src);

    const int GB = (N + 63) / 64;  // gemm blocks

    // 3) h1s = (x @ W1) * dinv
    gemm_tile_kernel<128, 64, 4, 4><<<GB, 256, 0, stream>>>(x, W1, dinv, h1s, N);

    // 4) h2 = relu(dinv*(gather h1s) + b1)
    gather_kernel<64, true><<<(N * 64 + 255) / 256, 256, 0, stream>>>(h1s, dinv, offs, csr_src, b1, h2, N);

    // 5) h3s = (h2 @ W2) * dinv
    gemm_tile_kernel<64, 32, 2, 4><<<GB, 256, 0, stream>>>(h2, W2, dinv, h3s, N);

    // 6) out = dinv*(gather h3s) + b2
    gather_kernel<32, false><<<(N * 32 + 255) / 256, 256, 0, stream>>>(h3s, dinv, offs, csr_src, b2, out, N);
}

// Round 5
// 698.356 us; speedup vs baseline: 2.4482x; 2.4482x over previous
//
#include <hip/hip_runtime.h>

// GCN 2-layer via CSR gather (no float atomics).
// R5: LDS-tiled GEMM with NAMED float4 registers (R4 spilled arrays to scratch).

// ---------------- degree ----------------
__global__ void deg_kernel(const int* __restrict__ dst, int E, int* __restrict__ deg) {
    int e = blockIdx.x * blockDim.x + threadIdx.x;
    if (e < E) atomicAdd(&deg[dst[e]], 1);
}

__global__ void dinv_kernel(const int* __restrict__ deg, float* __restrict__ dinv, int N) {
    int i = blockIdx.x * blockDim.x + threadIdx.x;
    if (i < N) dinv[i] = rsqrtf((float)deg[i] + 1.0f);  // +1 = self-loop
}

// ---------------- scan: offs = exclusive_scan(deg), offs[N] = E ----------------
__global__ void blocksum_kernel(const int* __restrict__ deg, int N, int* __restrict__ bsum) {
    __shared__ int s[256];
    int i = blockIdx.x * 256 + threadIdx.x;
    s[threadIdx.x] = (i < N) ? deg[i] : 0;
    __syncthreads();
    for (int o = 128; o > 0; o >>= 1) {
        if (threadIdx.x < o) s[threadIdx.x] += s[threadIdx.x + o];
        __syncthreads();
    }
    if (threadIdx.x == 0) bsum[blockIdx.x] = s[0];
}

__global__ void scan_bsum_kernel(int* __restrict__ bsum, int NB) {
    __shared__ int s[1024];
    int t = threadIdx.x;
    int v = (t < NB) ? bsum[t] : 0;
    s[t] = v;
    __syncthreads();
    for (int off = 1; off < 1024; off <<= 1) {
        int x = (t >= off) ? s[t - off] : 0;
        __syncthreads();
        s[t] += x;
        __syncthreads();
    }
    if (t < NB) bsum[t] = s[t] - v;  // exclusive, in place
}

__global__ void offsets_kernel(const int* __restrict__ deg, const int* __restrict__ bsum,
                               int* __restrict__ offs, int N, int E) {
    __shared__ int s[256];
    int t = threadIdx.x;
    int i = blockIdx.x * 256 + t;
    int v = (i < N) ? deg[i] : 0;
    s[t] = v;
    __syncthreads();
    for (int off = 1; off < 256; off <<= 1) {
        int x = (t >= off) ? s[t - off] : 0;
        __syncthreads();
        s[t] += x;
        __syncthreads();
    }
    if (i < N) offs[i] = bsum[blockIdx.x] + s[t] - v;
    if (i == 0) offs[N] = E;
}

__global__ void copy_kernel(const int* __restrict__ a, int* __restrict__ b, int N) {
    int i = blockIdx.x * blockDim.x + threadIdx.x;
    if (i < N) b[i] = a[i];
}

// ---------------- CSR fill: csr_src grouped by dst ----------------
__global__ void fill_kernel(const int* __restrict__ src, const int* __restrict__ dst, int E,
                            int* __restrict__ cursor, int* __restrict__ csr_src) {
    int e = blockIdx.x * blockDim.x + threadIdx.x;
    if (e < E) {
        int pos = atomicAdd(&cursor[dst[e]], 1);
        csr_src[pos] = src[e];
    }
}

// ---------------- LDS-tiled GEMM: out[r,c] = (A[r,:]@W[:,c]) * dinv[r] ----------------
// 256 threads; BR rows/block; each thread computes 4 rows x 4 cols, all state in
// NAMED float4 registers (no arrays -> no scratch).
#define FMA4(ACC, AV, WV) \
    ACC.x += (AV) * (WV).x; ACC.y += (AV) * (WV).y; ACC.z += (AV) * (WV).z; ACC.w += (AV) * (WV).w;

template <int K, int C, int BR>
__global__ void __launch_bounds__(256) gemm_tile_kernel(
        const float* __restrict__ A, const float* __restrict__ W,
        const float* __restrict__ dinv, float* __restrict__ out, int N) {
    constexpr int AL = K + 4;    // padded A row stride (floats), float4-aligned
    constexpr int F4R = K / 4;   // float4 per A row
    constexpr int CG = C / 4;    // column groups (CB=4)
    static_assert(256 / CG * 4 == BR, "geometry");
    __shared__ float Wl[K * C];
    __shared__ float Al[BR * AL];

    const int t = threadIdx.x;
    for (int i = t; i < K * C / 4; i += 256) ((float4*)Wl)[i] = ((const float4*)W)[i];
    const int row0 = blockIdx.x * BR;
    for (int i = t; i < BR * F4R; i += 256) {
        int r = i / F4R, k4 = i % F4R;
        float4 v = make_float4(0.f, 0.f, 0.f, 0.f);
        if (row0 + r < N) v = ((const float4*)(A + (size_t)(row0 + r) * K))[k4];
        *(float4*)(Al + r * AL + k4 * 4) = v;
    }
    __syncthreads();

    const int c0 = (t % CG) * 4;
    const int r0 = (t / CG) * 4;
    const float* Ab = Al + r0 * AL;

    float4 acc0 = {0, 0, 0, 0}, acc1 = {0, 0, 0, 0}, acc2 = {0, 0, 0, 0}, acc3 = {0, 0, 0, 0};

#pragma unroll
    for (int k4 = 0; k4 < K / 4; ++k4) {
        float4 a0 = *(const float4*)(Ab + 0 * AL + k4 * 4);
        float4 a1 = *(const float4*)(Ab + 1 * AL + k4 * 4);
        float4 a2 = *(const float4*)(Ab + 2 * AL + k4 * 4);
        float4 a3 = *(const float4*)(Ab + 3 * AL + k4 * 4);
        float4 w0 = *(const float4*)(Wl + (k4 * 4 + 0) * C + c0);
        float4 w1 = *(const float4*)(Wl + (k4 * 4 + 1) * C + c0);
        float4 w2 = *(const float4*)(Wl + (k4 * 4 + 2) * C + c0);
        float4 w3 = *(const float4*)(Wl + (k4 * 4 + 3) * C + c0);
        FMA4(acc0, a0.x, w0) FMA4(acc1, a1.x, w0) FMA4(acc2, a2.x, w0) FMA4(acc3, a3.x, w0)
        FMA4(acc0, a0.y, w1) FMA4(acc1, a1.y, w1) FMA4(acc2, a2.y, w1) FMA4(acc3, a3.y, w1)
        FMA4(acc0, a0.z, w2) FMA4(acc1, a1.z, w2) FMA4(acc2, a2.z, w2) FMA4(acc3, a3.z, w2)
        FMA4(acc0, a0.w, w3) FMA4(acc1, a1.w, w3) FMA4(acc2, a2.w, w3) FMA4(acc3, a3.w, w3)
    }

    int row = row0 + r0;
    if (row + 3 < N) {
        float d0 = dinv[row], d1 = dinv[row + 1], d2 = dinv[row + 2], d3 = dinv[row + 3];
        float4 r;
        r.x = acc0.x * d0; r.y = acc0.y * d0; r.z = acc0.z * d0; r.w = acc0.w * d0;
        *(float4*)(out + (size_t)row * C + c0) = r;
        r.x = acc1.x * d1; r.y = acc1.y * d1; r.z = acc1.z * d1; r.w = acc1.w * d1;
        *(float4*)(out + (size_t)(row + 1) * C + c0) = r;
        r.x = acc2.x * d2; r.y = acc2.y * d2; r.z = acc2.z * d2; r.w = acc2.w * d2;
        *(float4*)(out + (size_t)(row + 2) * C + c0) = r;
        r.x = acc3.x * d3; r.y = acc3.y * d3; r.z = acc3.z * d3; r.w = acc3.w * d3;
        *(float4*)(out + (size_t)(row + 3) * C + c0) = r;
    } else {
        if (row < N) {
            float d = dinv[row];
            float4 r = {acc0.x * d, acc0.y * d, acc0.z * d, acc0.w * d};
            *(float4*)(out + (size_t)row * C + c0) = r;
        }
        if (row + 1 < N) {
            float d = dinv[row + 1];
            float4 r = {acc1.x * d, acc1.y * d, acc1.z * d, acc1.w * d};
            *(float4*)(out + (size_t)(row + 1) * C + c0) = r;
        }
        if (row + 2 < N) {
            float d = dinv[row + 2];
            float4 r = {acc2.x * d, acc2.y * d, acc2.z * d, acc2.w * d};
            *(float4*)(out + (size_t)(row + 2) * C + c0) = r;
        }
        if (row + 3 < N) {
            float d = dinv[row + 3];
            float4 r = {acc3.x * d, acc3.y * d, acc3.z * d, acc3.w * d};
            *(float4*)(out + (size_t)(row + 3) * C + c0) = r;
        }
    }
}

// ---------------- gather: out[d] = dinv[d]*(sum_{s in N(d)} hs[s] + hs[d]) + b, optional relu
template <int C, bool RELU>
__global__ void gather_kernel(const float* __restrict__ hs, const float* __restrict__ dinv,
                              const int* __restrict__ offs, const int* __restrict__ csr_src,
                              const float* __restrict__ b, float* __restrict__ out, int N) {
    int gtid = blockIdx.x * blockDim.x + threadIdx.x;
    int lane = gtid % C;
    int d = gtid / C;
    if (d >= N) return;
    float acc = hs[(size_t)d * C + lane];  // self-loop term
    int beg = offs[d];
    int end = offs[d + 1];
    int j = beg;
    for (; j + 1 < end; j += 2) {
        int s0 = csr_src[j];
        int s1 = csr_src[j + 1];
        float v0 = hs[(size_t)s0 * C + lane];
        float v1 = hs[(size_t)s1 * C + lane];
        acc += v0;
        acc += v1;
    }
    if (j < end) acc += hs[(size_t)csr_src[j] * C + lane];
    float r = acc * dinv[d] + b[lane];
    if (RELU) r = fmaxf(r, 0.f);
    out[(size_t)d * C + lane] = r;
}

extern "C" void kernel_launch(void* const* d_in, const int* in_sizes, int n_in,
                              void* d_out, int out_size, void* d_ws, size_t ws_size,
                              hipStream_t stream) {
    const float* x = (const float*)d_in[0];
    const int* ei = (const int*)d_in[1];
    const float* W1 = (const float*)d_in[2];
    const float* b1 = (const float*)d_in[3];
    const float* W2 = (const float*)d_in[4];
    const float* b2 = (const float*)d_in[5];

    const int N = in_sizes[0] / 128;  // 100000
    const int E = in_sizes[1] / 2;    // 1600000
    const int* src = ei;
    const int* dst = ei + E;
    const int NB = (N + 255) / 256;   // 391 scan blocks (<= 1024)

    // workspace layout (4-byte elements)
    int* deg = (int*)d_ws;                         // N
    float* dinv = (float*)(deg + NB * 256);        // N
    int* offs = (int*)(dinv + NB * 256);           // N+1 (pad to 256)
    int* cursor = offs + NB * 256 + 256;           // N
    int* bsum = cursor + NB * 256;                 // NB (pad 1024)
    int* csr_src = bsum + 1024;                    // E
    float* h1s = (float*)(csr_src + ((E + 63) & ~63));  // N*64
    float* h2 = h1s + (size_t)N * 64;              // N*64
    float* h3s = h1s;                              // reuse h1s (N*32)
    float* out = (float*)d_out;

    // 1) degrees -> dinv
    hipMemsetAsync(deg, 0, (size_t)N * 4, stream);
    deg_kernel<<<(E + 255) / 256, 256, 0, stream>>>(dst, E, deg);
    dinv_kernel<<<NB, 256, 0, stream>>>(deg, dinv, N);

    // 2) CSR: offs = exscan(deg); fill csr_src grouped by dst
    blocksum_kernel<<<NB, 256, 0, stream>>>(deg, N, bsum);
    scan_bsum_kernel<<<1, 1024, 0, stream>>>(bsum, NB);
    offsets_kernel<<<NB, 256, 0, stream>>>(deg, bsum, offs, N, E);
    copy_kernel<<<NB, 256, 0, stream>>>(offs, cursor, N);
    fill_kernel<<<(E + 255) / 256, 256, 0, stream>>>(src, dst, E, cursor, csr_src);

    // 3) h1s = (x @ W1) * dinv     (BR=64: 16 colgroups x 16 rowgroups x 4 rows)
    gemm_tile_kernel<128, 64, 64><<<(N + 63) / 64, 256, 0, stream>>>(x, W1, dinv, h1s, N);

    // 4) h2 = relu(dinv*(gather h1s) + b1)
    gather_kernel<64, true><<<(N * 64 + 255) / 256, 256, 0, stream>>>(h1s, dinv, offs, csr_src, b1, h2, N);

    // 5) h3s = (h2 @ W2) * dinv    (BR=128: 8 colgroups x 32 rowgroups x 4 rows)
    gemm_tile_kernel<64, 32, 128><<<(N + 127) / 128, 256, 0, stream>>>(h2, W2, dinv, h3s, N);

    // 6) out = dinv*(gather h3s) + b2
    gather_kernel<32, false><<<(N * 32 + 255) / 256, 256, 0, stream>>>(h3s, dinv, offs, csr_src, b2, out, N);
}

// Round 6
// 421.647 us; speedup vs baseline: 4.0548x; 1.6563x over previous
//
#include <hip/hip_runtime.h>

// GCN 2-layer via CSR gather (no float atomics).
// R6: fix GEMM spill -- #pragma unroll 2 on k-loop (full unroll blew VGPRs),
// unpadded A tile (reads are broadcast, pad was useless), smaller LDS.

// ---------------- degree ----------------
__global__ void deg_kernel(const int* __restrict__ dst, int E, int* __restrict__ deg) {
    int e = blockIdx.x * blockDim.x + threadIdx.x;
    if (e < E) atomicAdd(&deg[dst[e]], 1);
}

__global__ void dinv_kernel(const int* __restrict__ deg, float* __restrict__ dinv, int N) {
    int i = blockIdx.x * blockDim.x + threadIdx.x;
    if (i < N) dinv[i] = rsqrtf((float)deg[i] + 1.0f);  // +1 = self-loop
}

// ---------------- scan: offs = exclusive_scan(deg), offs[N] = E ----------------
__global__ void blocksum_kernel(const int* __restrict__ deg, int N, int* __restrict__ bsum) {
    __shared__ int s[256];
    int i = blockIdx.x * 256 + threadIdx.x;
    s[threadIdx.x] = (i < N) ? deg[i] : 0;
    __syncthreads();
    for (int o = 128; o > 0; o >>= 1) {
        if (threadIdx.x < o) s[threadIdx.x] += s[threadIdx.x + o];
        __syncthreads();
    }
    if (threadIdx.x == 0) bsum[blockIdx.x] = s[0];
}

__global__ void scan_bsum_kernel(int* __restrict__ bsum, int NB) {
    __shared__ int s[1024];
    int t = threadIdx.x;
    int v = (t < NB) ? bsum[t] : 0;
    s[t] = v;
    __syncthreads();
    for (int off = 1; off < 1024; off <<= 1) {
        int x = (t >= off) ? s[t - off] : 0;
        __syncthreads();
        s[t] += x;
        __syncthreads();
    }
    if (t < NB) bsum[t] = s[t] - v;  // exclusive, in place
}

__global__ void offsets_kernel(const int* __restrict__ deg, const int* __restrict__ bsum,
                               int* __restrict__ offs, int N, int E) {
    __shared__ int s[256];
    int t = threadIdx.x;
    int i = blockIdx.x * 256 + t;
    int v = (i < N) ? deg[i] : 0;
    s[t] = v;
    __syncthreads();
    for (int off = 1; off < 256; off <<= 1) {
        int x = (t >= off) ? s[t - off] : 0;
        __syncthreads();
        s[t] += x;
        __syncthreads();
    }
    if (i < N) offs[i] = bsum[blockIdx.x] + s[t] - v;
    if (i == 0) offs[N] = E;
}

__global__ void copy_kernel(const int* __restrict__ a, int* __restrict__ b, int N) {
    int i = blockIdx.x * blockDim.x + threadIdx.x;
    if (i < N) b[i] = a[i];
}

// ---------------- CSR fill: csr_src grouped by dst ----------------
__global__ void fill_kernel(const int* __restrict__ src, const int* __restrict__ dst, int E,
                            int* __restrict__ cursor, int* __restrict__ csr_src) {
    int e = blockIdx.x * blockDim.x + threadIdx.x;
    if (e < E) {
        int pos = atomicAdd(&cursor[dst[e]], 1);
        csr_src[pos] = src[e];
    }
}

// ---------------- LDS-tiled GEMM: out[r,c] = (A[r,:]@W[:,c]) * dinv[r] ----------------
// 256 threads; BR rows/block; thread computes 4 rows x 4 cols in named float4 regs.
// k-loop unrolled only 2x: full unroll hoisted all LDS loads -> 256 VGPR + scratch spill (R5).
#define FMA4(ACC, AV, WV) \
    ACC.x += (AV) * (WV).x; ACC.y += (AV) * (WV).y; ACC.z += (AV) * (WV).z; ACC.w += (AV) * (WV).w;

template <int K, int C, int BR>
__global__ void __launch_bounds__(256) gemm_tile_kernel(
        const float* __restrict__ A, const float* __restrict__ W,
        const float* __restrict__ dinv, float* __restrict__ out, int N) {
    constexpr int F4R = K / 4;   // float4 per A row
    constexpr int CG = C / 4;    // column groups (4 cols per thread)
    static_assert(256 / CG * 4 == BR, "geometry");
    __shared__ float Wl[K * C];
    __shared__ float Al[BR * K];  // unpadded: A reads are 4-addr broadcast, no conflicts

    const int t = threadIdx.x;
    for (int i = t; i < K * C / 4; i += 256) ((float4*)Wl)[i] = ((const float4*)W)[i];
    const int row0 = blockIdx.x * BR;
    for (int i = t; i < BR * F4R; i += 256) {
        int r = i / F4R, k4 = i % F4R;
        float4 v = make_float4(0.f, 0.f, 0.f, 0.f);
        if (row0 + r < N) v = ((const float4*)(A + (size_t)(row0 + r) * K))[k4];
        *(float4*)(Al + r * K + k4 * 4) = v;
    }
    __syncthreads();

    const int c0 = (t % CG) * 4;
    const int r0 = (t / CG) * 4;
    const float* Ab = Al + r0 * K;

    float4 acc0 = {0, 0, 0, 0}, acc1 = {0, 0, 0, 0}, acc2 = {0, 0, 0, 0}, acc3 = {0, 0, 0, 0};

#pragma unroll 2
    for (int k4 = 0; k4 < K / 4; ++k4) {
        float4 a0 = *(const float4*)(Ab + 0 * K + k4 * 4);
        float4 a1 = *(const float4*)(Ab + 1 * K + k4 * 4);
        float4 a2 = *(const float4*)(Ab + 2 * K + k4 * 4);
        float4 a3 = *(const float4*)(Ab + 3 * K + k4 * 4);
        float4 w0 = *(const float4*)(Wl + (k4 * 4 + 0) * C + c0);
        float4 w1 = *(const float4*)(Wl + (k4 * 4 + 1) * C + c0);
        float4 w2 = *(const float4*)(Wl + (k4 * 4 + 2) * C + c0);
        float4 w3 = *(const float4*)(Wl + (k4 * 4 + 3) * C + c0);
        FMA4(acc0, a0.x, w0) FMA4(acc1, a1.x, w0) FMA4(acc2, a2.x, w0) FMA4(acc3, a3.x, w0)
        FMA4(acc0, a0.y, w1) FMA4(acc1, a1.y, w1) FMA4(acc2, a2.y, w1) FMA4(acc3, a3.y, w1)
        FMA4(acc0, a0.z, w2) FMA4(acc1, a1.z, w2) FMA4(acc2, a2.z, w2) FMA4(acc3, a3.z, w2)
        FMA4(acc0, a0.w, w3) FMA4(acc1, a1.w, w3) FMA4(acc2, a2.w, w3) FMA4(acc3, a3.w, w3)
    }

    int row = row0 + r0;
    if (row + 3 < N) {
        float d0 = dinv[row], d1 = dinv[row + 1], d2 = dinv[row + 2], d3 = dinv[row + 3];
        float4 r;
        r.x = acc0.x * d0; r.y = acc0.y * d0; r.z = acc0.z * d0; r.w = acc0.w * d0;
        *(float4*)(out + (size_t)row * C + c0) = r;
        r.x = acc1.x * d1; r.y = acc1.y * d1; r.z = acc1.z * d1; r.w = acc1.w * d1;
        *(float4*)(out + (size_t)(row + 1) * C + c0) = r;
        r.x = acc2.x * d2; r.y = acc2.y * d2; r.z = acc2.z * d2; r.w = acc2.w * d2;
        *(float4*)(out + (size_t)(row + 2) * C + c0) = r;
        r.x = acc3.x * d3; r.y = acc3.y * d3; r.z = acc3.z * d3; r.w = acc3.w * d3;
        *(float4*)(out + (size_t)(row + 3) * C + c0) = r;
    } else {
        if (row < N) {
            float d = dinv[row];
            float4 r = {acc0.x * d, acc0.y * d, acc0.z * d, acc0.w * d};
            *(float4*)(out + (size_t)row * C + c0) = r;
        }
        if (row + 1 < N) {
            float d = dinv[row + 1];
            float4 r = {acc1.x * d, acc1.y * d, acc1.z * d, acc1.w * d};
            *(float4*)(out + (size_t)(row + 1) * C + c0) = r;
        }
        if (row + 2 < N) {
            float d = dinv[row + 2];
            float4 r = {acc2.x * d, acc2.y * d, acc2.z * d, acc2.w * d};
            *(float4*)(out + (size_t)(row + 2) * C + c0) = r;
        }
        if (row + 3 < N) {
            float d = dinv[row + 3];
            float4 r = {acc3.x * d, acc3.y * d, acc3.z * d, acc3.w * d};
            *(float4*)(out + (size_t)(row + 3) * C + c0) = r;
        }
    }
}

// ---------------- gather: out[d] = dinv[d]*(sum_{s in N(d)} hs[s] + hs[d]) + b, optional relu
template <int C, bool RELU>
__global__ void gather_kernel(const float* __restrict__ hs, const float* __restrict__ dinv,
                              const int* __restrict__ offs, const int* __restrict__ csr_src,
                              const float* __restrict__ b, float* __restrict__ out, int N) {
    int gtid = blockIdx.x * blockDim.x + threadIdx.x;
    int lane = gtid % C;
    int d = gtid / C;
    if (d >= N) return;
    float acc = hs[(size_t)d * C + lane];  // self-loop term
    int beg = offs[d];
    int end = offs[d + 1];
    int j = beg;
    for (; j + 1 < end; j += 2) {
        int s0 = csr_src[j];
        int s1 = csr_src[j + 1];
        float v0 = hs[(size_t)s0 * C + lane];
        float v1 = hs[(size_t)s1 * C + lane];
        acc += v0;
        acc += v1;
    }
    if (j < end) acc += hs[(size_t)csr_src[j] * C + lane];
    float r = acc * dinv[d] + b[lane];
    if (RELU) r = fmaxf(r, 0.f);
    out[(size_t)d * C + lane] = r;
}

extern "C" void kernel_launch(void* const* d_in, const int* in_sizes, int n_in,
                              void* d_out, int out_size, void* d_ws, size_t ws_size,
                              hipStream_t stream) {
    const float* x = (const float*)d_in[0];
    const int* ei = (const int*)d_in[1];
    const float* W1 = (const float*)d_in[2];
    const float* b1 = (const float*)d_in[3];
    const float* W2 = (const float*)d_in[4];
    const float* b2 = (const float*)d_in[5];

    const int N = in_sizes[0] / 128;  // 100000
    const int E = in_sizes[1] / 2;    // 1600000
    const int* src = ei;
    const int* dst = ei + E;
    const int NB = (N + 255) / 256;   // 391 scan blocks (<= 1024)

    // workspace layout (4-byte elements)
    int* deg = (int*)d_ws;                         // N
    float* dinv = (float*)(deg + NB * 256);        // N
    int* offs = (int*)(dinv + NB * 256);           // N+1 (pad to 256)
    int* cursor = offs + NB * 256 + 256;           // N
    int* bsum = cursor + NB * 256;                 // NB (pad 1024)
    int* csr_src = bsum + 1024;                    // E
    float* h1s = (float*)(csr_src + ((E + 63) & ~63));  // N*64
    float* h2 = h1s + (size_t)N * 64;              // N*64
    float* h3s = h1s;                              // reuse h1s (N*32)
    float* out = (float*)d_out;

    // 1) degrees -> dinv
    hipMemsetAsync(deg, 0, (size_t)N * 4, stream);
    deg_kernel<<<(E + 255) / 256, 256, 0, stream>>>(dst, E, deg);
    dinv_kernel<<<NB, 256, 0, stream>>>(deg, dinv, N);

    // 2) CSR: offs = exscan(deg); fill csr_src grouped by dst
    blocksum_kernel<<<NB, 256, 0, stream>>>(deg, N, bsum);
    scan_bsum_kernel<<<1, 1024, 0, stream>>>(bsum, NB);
    offsets_kernel<<<NB, 256, 0, stream>>>(deg, bsum, offs, N, E);
    copy_kernel<<<NB, 256, 0, stream>>>(offs, cursor, N);
    fill_kernel<<<(E + 255) / 256, 256, 0, stream>>>(src, dst, E, cursor, csr_src);

    // 3) h1s = (x @ W1) * dinv     (BR=64: 16 colgroups, LDS 64KB)
    gemm_tile_kernel<128, 64, 64><<<(N + 63) / 64, 256, 0, stream>>>(x, W1, dinv, h1s, N);

    // 4) h2 = relu(dinv*(gather h1s) + b1)
    gather_kernel<64, true><<<(N * 64 + 255) / 256, 256, 0, stream>>>(h1s, dinv, offs, csr_src, b1, h2, N);

    // 5) h3s = (h2 @ W2) * dinv    (BR=128: 8 colgroups, LDS 40KB)
    gemm_tile_kernel<64, 32, 128><<<(N + 127) / 128, 256, 0, stream>>>(h2, W2, dinv, h3s, N);

    // 6) out = dinv*(gather h3s) + b2
    gather_kernel<32, false><<<(N * 32 + 255) / 256, 256, 0, stream>>>(h3s, dinv, offs, csr_src, b2, out, N);
}